// Round 18
// baseline (197.522 us; speedup 1.0000x reference)
//
#include <hip/hip_runtime.h>

// GCN 2-layer, N=100000, E=3200000, 13 -> 32 -> 16.
// v16 = v15 (193.9us) with binA at 1024thr x 12 edges/thread (TILE=12288,
// grid=261): bucket runs 21 -> ~31 edges (write-amp ~2x -> ~1.6x, the
// R14/R16-validated lever) AND full-CU occupancy (16 waves/CU everywhere).
// binB(1024thr)/agg_mlp/agg byte-identical to v15.

constexpr int N_NODES = 100000;
constexpr int N_EDGES = 3200000;
constexpr int IN_CH  = 13;
constexpr int HID_CH = 32;
constexpr int LAT_CH = 16;

constexpr int NPB  = 256;                          // nodes per bucket (dst>>8)
constexpr int NBKT = (N_NODES + NPB - 1) / NPB;    // 391
constexpr int BCAP = 8960;                         // mean 8192, sd ~90 -> +8.5 sigma
constexpr int EPT  = 12;                           // edges per binA thread
constexpr int TILE = 1024 * EPT;                   // 12288 edges per binA block

__global__ __launch_bounds__(512) void k_zero_bcur(int* __restrict__ bcur) {
    int i = threadIdx.x;
    if (i < NBKT) bcur[i] = 0;
}

// bin edges into coarse bucket regions; packed word = (dst&255)<<17 | src.
// One pass: 12 edges/thread staged in registers (3x int4, per-int4 tail guard;
// N_EDGES%4==0 so each int4 is all-or-nothing).
__global__ __launch_bounds__(1024) void k_binA(const int* __restrict__ src,
                                               const int* __restrict__ dst,
                                               int* __restrict__ bcur,
                                               int* __restrict__ buckets) {
    __shared__ int h[NBKT], st[NBKT], cur[NBKT];
    int tid = threadIdx.x;
    for (int i = tid; i < NBKT; i += 1024) h[i] = 0;
    __syncthreads();
    int base = blockIdx.x * TILE + tid * EPT;
    int d[EPT], s[EPT];
    bool hv[3];
#pragma unroll
    for (int g = 0; g < 3; ++g) hv[g] = (base + g * 4) < N_EDGES;
    const int4* dp = (const int4*)(dst + base);
    const int4* sp = (const int4*)(src + base);
#pragma unroll
    for (int g = 0; g < 3; ++g) {
        if (hv[g]) {
            int4 dv = dp[g];
            int4 sv = sp[g];
            d[g * 4 + 0] = dv.x; d[g * 4 + 1] = dv.y;
            d[g * 4 + 2] = dv.z; d[g * 4 + 3] = dv.w;
            s[g * 4 + 0] = sv.x; s[g * 4 + 1] = sv.y;
            s[g * 4 + 2] = sv.z; s[g * 4 + 3] = sv.w;
        } else {
            d[g * 4 + 0] = d[g * 4 + 1] = d[g * 4 + 2] = d[g * 4 + 3] = -1;
            s[g * 4 + 0] = s[g * 4 + 1] = s[g * 4 + 2] = s[g * 4 + 3] = 0;
        }
    }
#pragma unroll
    for (int j = 0; j < EPT; ++j)
        if (d[j] >= 0) atomicAdd(&h[d[j] >> 8], 1);
    __syncthreads();
    for (int i = tid; i < NBKT; i += 1024) {
        int c = h[i];
        st[i] = c > 0 ? atomicAdd(&bcur[i], c) : 0;
        cur[i] = 0;
    }
    __syncthreads();
#pragma unroll
    for (int j = 0; j < EPT; ++j) {
        if (d[j] >= 0) {
            int b = d[j] >> 8;
            int r = atomicAdd(&cur[b], 1);
            buckets[b * BCAP + st[b] + r] = s[j] | ((d[j] & 255) << 17);
        }
    }
}

// per-bucket counting sort, fully in LDS (v15 verbatim, 1024 threads):
// top-scan confined to tid<512 (all threads hit barriers); strided loops 1024.
__global__ __launch_bounds__(1024) void k_binB(const int* __restrict__ bcur,
                                               const int* __restrict__ buckets,
                                               const float* __restrict__ x,
                                               int* __restrict__ off,
                                               float* __restrict__ dis,
                                               int* __restrict__ srcs,
                                               float* __restrict__ xn) {
    __shared__ int wbuf[BCAP];     // staged bucket words
    __shared__ int sorted_[BCAP];  // sorted src ids
    __shared__ int h[NPB], ex[NPB], curso[NPB];
    __shared__ int sv[512];        // top-level scan buffer
    __shared__ float sdis[NPB];
    int b = blockIdx.x, tid = threadIdx.x;

    // local top scan (inclusive over 512 slots, zeros beyond NBKT)
    if (tid < 512) sv[tid] = (tid < NBKT) ? bcur[tid] : 0;
    __syncthreads();
    for (int d = 1; d < 512; d <<= 1) {
        int a = 0, u = 0;
        if (tid < 512) {
            a = sv[tid];
            u = (tid >= d) ? sv[tid - d] : 0;
        }
        __syncthreads();
        if (tid < 512) sv[tid] = a + u;
        __syncthreads();
    }
    int base = (b > 0) ? sv[b - 1] : 0;     // exclusive prefix for bucket b
    int cntb = bcur[b];
    if (cntb > BCAP) cntb = BCAP;
    const int* bw = buckets + b * BCAP;

    for (int i = tid; i < cntb; i += 1024) wbuf[i] = bw[i];
    if (tid < NPB) h[tid] = 0;
    __syncthreads();
    for (int i = tid; i < cntb; i += 1024) atomicAdd(&h[wbuf[i] >> 17], 1);
    __syncthreads();
    int node0 = b * NPB;
    if (tid < NPB) {
        int node = node0 + tid;
        float dv = rsqrtf((float)(h[tid] + 1));   // +1 self-loop
        sdis[tid] = dv;
        if (node < N_NODES) dis[node] = dv;
        ex[tid] = h[tid];
    }
    __syncthreads();
    for (int d = 1; d < NPB; d <<= 1) {    // inclusive scan over 256
        int a = 0, u = 0;
        if (tid < NPB) a = ex[tid];
        if (tid >= d && tid < NPB) u = ex[tid - d];
        __syncthreads();
        if (tid < NPB) ex[tid] = a + u;
        __syncthreads();
    }
    if (tid < NPB) {
        int excl = ex[tid] - h[tid];
        int node = node0 + tid;
        if (node < N_NODES) off[node] = base + excl;
        curso[tid] = excl;
    }
    if (b == 0 && tid == 0) off[N_NODES] = N_EDGES;
    __syncthreads();
    for (int i = tid; i < cntb; i += 1024) {
        int w = wbuf[i];
        int r = atomicAdd(&curso[w >> 17], 1);
        sorted_[r] = w & 131071;
    }
    __syncthreads();
    for (int i = tid; i < cntb; i += 1024) srcs[base + i] = sorted_[i];
    // fused xn emission for this bucket's nodes
    for (int i = tid; i < NPB * 16; i += 1024) {
        int nl = i >> 4, c = i & 15;
        int node = node0 + nl;
        if (node < N_NODES)
            xn[node * 16 + c] = (c < IN_CH) ? x[node * IN_CH + c] * sdis[nl] : 0.f;
    }
}

// Layer-1 aggregation with FUSED MLP epilogue (v13 verbatim).
__global__ __launch_bounds__(256) void k_agg_mlp(const int* __restrict__ off,
                                                 const int* __restrict__ srcs,
                                                 const float* __restrict__ dis,
                                                 const float* __restrict__ vin,
                                                 const float* __restrict__ W1,
                                                 const float* __restrict__ b1,
                                                 const float* __restrict__ W2,
                                                 float* __restrict__ hwn) {
    __shared__ float sW1[IN_CH * HID_CH];     // 416 f
    __shared__ float sW2[HID_CH * LAT_CH];    // 512 f
    __shared__ float sb1[HID_CH];
    __shared__ float s1b[16][16];             // per-node s1 rows
    __shared__ float hb[16][HID_CH + 1];      // per-node hidden (pad 33)
    __shared__ float sdisb[16];
    int tid = threadIdx.x;
    for (int i = tid; i < IN_CH * HID_CH; i += 256) sW1[i] = W1[i];
    for (int i = tid; i < HID_CH * LAT_CH; i += 256) sW2[i] = W2[i];
    if (tid < HID_CH) sb1[tid] = b1[tid];
    __syncthreads();                           // weights visible to all waves

    int wave = (blockIdx.x * 256 + tid) >> 6;
    int lane = tid & 63;
    int q    = lane & 3;           // channel quad
    int esub = (lane >> 2) & 3;    // edge slot 0..3 (+4 second window)
    int nsub = lane >> 4;          // node sub-index 0..3
    int node = wave * 4 + nsub;
    bool valid = node < N_NODES;
    int beg = valid ? off[node] : 0;
    int end = valid ? off[node + 1] : 0;

    float ax = 0.f, ay = 0.f, az = 0.f, aw = 0.f;
    int k1 = beg + esub;
    int k2 = k1 + 4;
    int s1 = (k1 < end) ? srcs[k1] : -1;
    int s2 = (k2 < end) ? srcs[k2] : -1;
    for (int kb = beg; kb < end; kb += 8) {
        int kn = kb + 8 + esub;
        int sn1 = (kn < end)     ? srcs[kn]     : -1;
        int sn2 = (kn + 4 < end) ? srcs[kn + 4] : -1;
        float4 v1, v2;
        v1.x = v1.y = v1.z = v1.w = 0.f;
        v2.x = v2.y = v2.z = v2.w = 0.f;
        if (s1 >= 0) v1 = *((const float4*)(vin + (size_t)s1 * 16) + q);
        if (s2 >= 0) v2 = *((const float4*)(vin + (size_t)s2 * 16) + q);
        ax += v1.x + v2.x;
        ay += v1.y + v2.y;
        az += v1.z + v2.z;
        aw += v1.w + v2.w;
        s1 = sn1; s2 = sn2;
    }
#pragma unroll
    for (int m = 4; m <= 8; m <<= 1) {
        ax += __shfl_xor(ax, m);
        ay += __shfl_xor(ay, m);
        az += __shfl_xor(az, m);
        aw += __shfl_xor(aw, m);
    }
    int nl = ((tid >> 6) << 2) | nsub;         // node index within block, 0..15
    if (esub == 0 && valid) {
        const float4 self = *((const float4*)(vin + (size_t)node * 16) + q);
        float d = dis[node];
        float4 r;
        r.x = d * (ax + self.x);
        r.y = d * (ay + self.y);
        r.z = d * (az + self.z);
        r.w = d * (aw + self.w);
        *((float4*)&s1b[nl][q * 4]) = r;       // row stride 64B: float4-aligned
        if (q == 0) sdisb[nl] = d;
    }
    // wave-local exchange: nl range of this wave == (tid>>4) range -> no barrier
    int node_l = tid >> 4, g = tid & 15;
    int gnode = blockIdx.x * 16 + node_l;
    if (gnode < N_NODES) {
        float s[16];
#pragma unroll
        for (int k = 0; k < 16; ++k) s[k] = s1b[node_l][k];
        float h0 = sb1[g], h1 = sb1[g + 16];
#pragma unroll
        for (int k = 0; k < IN_CH; ++k) {
            h0 += s[k] * sW1[k * HID_CH + g];
            h1 += s[k] * sW1[k * HID_CH + g + 16];
        }
        hb[node_l][g]      = h0 > 0.f ? h0 : 0.f;
        hb[node_l][g + 16] = h1 > 0.f ? h1 : 0.f;
        float o = 0.f;
#pragma unroll
        for (int k = 0; k < HID_CH; ++k)
            o += hb[node_l][k] * sW2[k * LAT_CH + g];
        hwn[(size_t)gnode * 16 + g] = o * sdisb[node_l];
    }
}

// Layer-2 aggregation (k_agg v3, unchanged): 4 nodes/wave, dual window.
// outv[d*16+ch] = dis[d] * (sum_edges vin[s*16+ch] + vin[d*16+ch]) + bias
__global__ __launch_bounds__(256) void k_agg(const int* __restrict__ off,
                                             const int* __restrict__ srcs,
                                             const float* __restrict__ dis,
                                             const float* __restrict__ vin,
                                             const float* __restrict__ bias,  // may be null
                                             float* __restrict__ outv) {
    int wave = (blockIdx.x * 256 + threadIdx.x) >> 6;
    int lane = threadIdx.x & 63;
    int q    = lane & 3;
    int esub = (lane >> 2) & 3;
    int nsub = lane >> 4;
    int node = wave * 4 + nsub;
    bool valid = node < N_NODES;
    int beg = valid ? off[node] : 0;
    int end = valid ? off[node + 1] : 0;

    float ax = 0.f, ay = 0.f, az = 0.f, aw = 0.f;
    int k1 = beg + esub;
    int k2 = k1 + 4;
    int s1 = (k1 < end) ? srcs[k1] : -1;
    int s2 = (k2 < end) ? srcs[k2] : -1;
    for (int kb = beg; kb < end; kb += 8) {
        int kn = kb + 8 + esub;
        int sn1 = (kn < end)     ? srcs[kn]     : -1;
        int sn2 = (kn + 4 < end) ? srcs[kn + 4] : -1;
        float4 v1, v2;
        v1.x = v1.y = v1.z = v1.w = 0.f;
        v2.x = v2.y = v2.z = v2.w = 0.f;
        if (s1 >= 0) v1 = *((const float4*)(vin + (size_t)s1 * 16) + q);
        if (s2 >= 0) v2 = *((const float4*)(vin + (size_t)s2 * 16) + q);
        ax += v1.x + v2.x;
        ay += v1.y + v2.y;
        az += v1.z + v2.z;
        aw += v1.w + v2.w;
        s1 = sn1; s2 = sn2;
    }
#pragma unroll
    for (int m = 4; m <= 8; m <<= 1) {
        ax += __shfl_xor(ax, m);
        ay += __shfl_xor(ay, m);
        az += __shfl_xor(az, m);
        aw += __shfl_xor(aw, m);
    }
    if (esub == 0 && valid) {
        const float4 self = *((const float4*)(vin + (size_t)node * 16) + q);
        float d = dis[node];
        float4 r;
        r.x = d * (ax + self.x);
        r.y = d * (ay + self.y);
        r.z = d * (az + self.z);
        r.w = d * (aw + self.w);
        if (bias) {
            const float4 bq = ((const float4*)bias)[q];
            r.x += bq.x; r.y += bq.y; r.z += bq.z; r.w += bq.w;
        }
        *((float4*)(outv + (size_t)node * 16) + q) = r;
    }
}

extern "C" void kernel_launch(void* const* d_in, const int* in_sizes, int n_in,
                              void* d_out, int out_size, void* d_ws, size_t ws_size,
                              hipStream_t stream) {
    const float* x  = (const float*)d_in[0];
    const int*   ei = (const int*)d_in[1];
    const float* W1 = (const float*)d_in[2];
    const float* b1 = (const float*)d_in[3];
    const float* W2 = (const float*)d_in[4];
    const float* b2 = (const float*)d_in[5];
    float* out = (float*)d_out;

    const int* src = ei;
    const int* dst = ei + N_EDGES;

    // ws layout (bytes):
    //   bcur[391] @ 0 (pad 4096) | off[N+1] @ 4096 | dis[N] @ 404160
    //   srcs[E]   @ 804160 (12.8MB)
    //   buckets   @ 13604160 (391*8960*4 = 14,013,440 -> ends 27,617,600)
    //   hwn       @ 20004160 (inside buckets; written post-binB, buckets dead;
    //                          must NOT alias xn: agg_mlp reads xn, writes hwn)
    //   xn        @ 27617600 (6.4MB own region; binB writes while buckets live)
    char* ws = (char*)d_ws;
    int*   bcur    = (int*)(ws);
    int*   off     = (int*)(ws + 4096);
    float* dis     = (float*)(ws + 404160);
    int*   srcs    = (int*)(ws + 804160);
    int*   buckets = (int*)(ws + 13604160);
    float* hwn     = (float*)(ws + 20004160);
    float* xn      = (float*)(ws + 27617600);

    const int NB_A  = (N_EDGES + TILE - 1) / TILE;      // 261
    const int NB_W  = (N_NODES + 15) / 16;              // 4 nodes/wave, 4 waves/block

    k_zero_bcur<<<1,    512, 0, stream>>>(bcur);
    k_binA     <<<NB_A, 1024, 0, stream>>>(src, dst, bcur, buckets);
    k_binB     <<<NBKT, 1024, 0, stream>>>(bcur, buckets, x, off, dis, srcs, xn);
    k_agg_mlp  <<<NB_W, 256, 0, stream>>>(off, srcs, dis, xn, W1, b1, W2, hwn);
    k_agg      <<<NB_W, 256, 0, stream>>>(off, srcs, dis, hwn, b2, out);
}

// Round 19
// 191.428 us; speedup vs baseline: 1.0318x; 1.0318x over previous
//
#include <hip/hip_runtime.h>

// GCN 2-layer, N=100000, E=3200000, 13 -> 32 -> 16.
// v17 = v15 verbatim (measured best, 193.9us): binA 512thr x 16 edges
// (TILE=8192), binB 1024thr, agg_mlp + agg (4 nodes/wave dual-window).
// v16's binA 1024x12 regressed (197.5) -> reverted. All phases at
// falsification-pinned structural floors.

constexpr int N_NODES = 100000;
constexpr int N_EDGES = 3200000;
constexpr int IN_CH  = 13;
constexpr int HID_CH = 32;
constexpr int LAT_CH = 16;

constexpr int NPB  = 256;                          // nodes per bucket (dst>>8)
constexpr int NBKT = (N_NODES + NPB - 1) / NPB;    // 391
constexpr int BCAP = 8960;                         // mean 8192, sd ~90 -> +8.5 sigma
constexpr int TILE = 8192;                         // edges per binA block (16/thread)

__global__ __launch_bounds__(512) void k_zero_bcur(int* __restrict__ bcur) {
    int i = threadIdx.x;
    if (i < NBKT) bcur[i] = 0;
}

// bin edges into coarse bucket regions; packed word = (dst&255)<<17 | src.
// One pass over the edge list: 16 edges/thread staged in registers (int4 x4).
__global__ __launch_bounds__(512) void k_binA(const int* __restrict__ src,
                                              const int* __restrict__ dst,
                                              int* __restrict__ bcur,
                                              int* __restrict__ buckets) {
    __shared__ int h[NBKT], st[NBKT], cur[NBKT];
    int tid = threadIdx.x;
    for (int i = tid; i < NBKT; i += 512) h[i] = 0;
    __syncthreads();
    int base16 = blockIdx.x * TILE + tid * 16;     // TILE = 512*16; groups never split
    int d[16], s[16];
    bool have = base16 < N_EDGES;
    if (have) {
        const int4* dp = (const int4*)(dst + base16);
        const int4* sp = (const int4*)(src + base16);
#pragma unroll
        for (int g = 0; g < 4; ++g) {
            int4 dv = dp[g];
            int4 sv = sp[g];
            d[g * 4 + 0] = dv.x; d[g * 4 + 1] = dv.y;
            d[g * 4 + 2] = dv.z; d[g * 4 + 3] = dv.w;
            s[g * 4 + 0] = sv.x; s[g * 4 + 1] = sv.y;
            s[g * 4 + 2] = sv.z; s[g * 4 + 3] = sv.w;
        }
#pragma unroll
        for (int j = 0; j < 16; ++j) atomicAdd(&h[d[j] >> 8], 1);
    }
    __syncthreads();
    for (int i = tid; i < NBKT; i += 512) {
        int c = h[i];
        st[i] = c > 0 ? atomicAdd(&bcur[i], c) : 0;
        cur[i] = 0;
    }
    __syncthreads();
    if (have) {
#pragma unroll
        for (int j = 0; j < 16; ++j) {
            int b = d[j] >> 8;
            int r = atomicAdd(&cur[b], 1);
            buckets[b * BCAP + st[b] + r] = s[j] | ((d[j] & 255) << 17);
        }
    }
}

// per-bucket counting sort, fully in LDS (1024 threads):
// top-scan confined to tid<512 (all threads hit barriers); strided loops 1024.
__global__ __launch_bounds__(1024) void k_binB(const int* __restrict__ bcur,
                                               const int* __restrict__ buckets,
                                               const float* __restrict__ x,
                                               int* __restrict__ off,
                                               float* __restrict__ dis,
                                               int* __restrict__ srcs,
                                               float* __restrict__ xn) {
    __shared__ int wbuf[BCAP];     // staged bucket words
    __shared__ int sorted_[BCAP];  // sorted src ids
    __shared__ int h[NPB], ex[NPB], curso[NPB];
    __shared__ int sv[512];        // top-level scan buffer
    __shared__ float sdis[NPB];
    int b = blockIdx.x, tid = threadIdx.x;

    // local top scan (inclusive over 512 slots, zeros beyond NBKT)
    if (tid < 512) sv[tid] = (tid < NBKT) ? bcur[tid] : 0;
    __syncthreads();
    for (int d = 1; d < 512; d <<= 1) {
        int a = 0, u = 0;
        if (tid < 512) {
            a = sv[tid];
            u = (tid >= d) ? sv[tid - d] : 0;
        }
        __syncthreads();
        if (tid < 512) sv[tid] = a + u;
        __syncthreads();
    }
    int base = (b > 0) ? sv[b - 1] : 0;     // exclusive prefix for bucket b
    int cntb = bcur[b];
    if (cntb > BCAP) cntb = BCAP;
    const int* bw = buckets + b * BCAP;

    for (int i = tid; i < cntb; i += 1024) wbuf[i] = bw[i];
    if (tid < NPB) h[tid] = 0;
    __syncthreads();
    for (int i = tid; i < cntb; i += 1024) atomicAdd(&h[wbuf[i] >> 17], 1);
    __syncthreads();
    int node0 = b * NPB;
    if (tid < NPB) {
        int node = node0 + tid;
        float dv = rsqrtf((float)(h[tid] + 1));   // +1 self-loop
        sdis[tid] = dv;
        if (node < N_NODES) dis[node] = dv;
        ex[tid] = h[tid];
    }
    __syncthreads();
    for (int d = 1; d < NPB; d <<= 1) {    // inclusive scan over 256
        int a = 0, u = 0;
        if (tid < NPB) a = ex[tid];
        if (tid >= d && tid < NPB) u = ex[tid - d];
        __syncthreads();
        if (tid < NPB) ex[tid] = a + u;
        __syncthreads();
    }
    if (tid < NPB) {
        int excl = ex[tid] - h[tid];
        int node = node0 + tid;
        if (node < N_NODES) off[node] = base + excl;
        curso[tid] = excl;
    }
    if (b == 0 && tid == 0) off[N_NODES] = N_EDGES;
    __syncthreads();
    for (int i = tid; i < cntb; i += 1024) {
        int w = wbuf[i];
        int r = atomicAdd(&curso[w >> 17], 1);
        sorted_[r] = w & 131071;
    }
    __syncthreads();
    for (int i = tid; i < cntb; i += 1024) srcs[base + i] = sorted_[i];
    // fused xn emission for this bucket's nodes
    for (int i = tid; i < NPB * 16; i += 1024) {
        int nl = i >> 4, c = i & 15;
        int node = node0 + nl;
        if (node < N_NODES)
            xn[node * 16 + c] = (c < IN_CH) ? x[node * IN_CH + c] * sdis[nl] : 0.f;
    }
}

// Layer-1 aggregation with FUSED MLP epilogue (v13 verbatim).
__global__ __launch_bounds__(256) void k_agg_mlp(const int* __restrict__ off,
                                                 const int* __restrict__ srcs,
                                                 const float* __restrict__ dis,
                                                 const float* __restrict__ vin,
                                                 const float* __restrict__ W1,
                                                 const float* __restrict__ b1,
                                                 const float* __restrict__ W2,
                                                 float* __restrict__ hwn) {
    __shared__ float sW1[IN_CH * HID_CH];     // 416 f
    __shared__ float sW2[HID_CH * LAT_CH];    // 512 f
    __shared__ float sb1[HID_CH];
    __shared__ float s1b[16][16];             // per-node s1 rows
    __shared__ float hb[16][HID_CH + 1];      // per-node hidden (pad 33)
    __shared__ float sdisb[16];
    int tid = threadIdx.x;
    for (int i = tid; i < IN_CH * HID_CH; i += 256) sW1[i] = W1[i];
    for (int i = tid; i < HID_CH * LAT_CH; i += 256) sW2[i] = W2[i];
    if (tid < HID_CH) sb1[tid] = b1[tid];
    __syncthreads();                           // weights visible to all waves

    int wave = (blockIdx.x * 256 + tid) >> 6;
    int lane = tid & 63;
    int q    = lane & 3;           // channel quad
    int esub = (lane >> 2) & 3;    // edge slot 0..3 (+4 second window)
    int nsub = lane >> 4;          // node sub-index 0..3
    int node = wave * 4 + nsub;
    bool valid = node < N_NODES;
    int beg = valid ? off[node] : 0;
    int end = valid ? off[node + 1] : 0;

    float ax = 0.f, ay = 0.f, az = 0.f, aw = 0.f;
    int k1 = beg + esub;
    int k2 = k1 + 4;
    int s1 = (k1 < end) ? srcs[k1] : -1;
    int s2 = (k2 < end) ? srcs[k2] : -1;
    for (int kb = beg; kb < end; kb += 8) {
        int kn = kb + 8 + esub;
        int sn1 = (kn < end)     ? srcs[kn]     : -1;
        int sn2 = (kn + 4 < end) ? srcs[kn + 4] : -1;
        float4 v1, v2;
        v1.x = v1.y = v1.z = v1.w = 0.f;
        v2.x = v2.y = v2.z = v2.w = 0.f;
        if (s1 >= 0) v1 = *((const float4*)(vin + (size_t)s1 * 16) + q);
        if (s2 >= 0) v2 = *((const float4*)(vin + (size_t)s2 * 16) + q);
        ax += v1.x + v2.x;
        ay += v1.y + v2.y;
        az += v1.z + v2.z;
        aw += v1.w + v2.w;
        s1 = sn1; s2 = sn2;
    }
#pragma unroll
    for (int m = 4; m <= 8; m <<= 1) {
        ax += __shfl_xor(ax, m);
        ay += __shfl_xor(ay, m);
        az += __shfl_xor(az, m);
        aw += __shfl_xor(aw, m);
    }
    int nl = ((tid >> 6) << 2) | nsub;         // node index within block, 0..15
    if (esub == 0 && valid) {
        const float4 self = *((const float4*)(vin + (size_t)node * 16) + q);
        float d = dis[node];
        float4 r;
        r.x = d * (ax + self.x);
        r.y = d * (ay + self.y);
        r.z = d * (az + self.z);
        r.w = d * (aw + self.w);
        *((float4*)&s1b[nl][q * 4]) = r;       // row stride 64B: float4-aligned
        if (q == 0) sdisb[nl] = d;
    }
    // wave-local exchange: nl range of this wave == (tid>>4) range -> no barrier
    int node_l = tid >> 4, g = tid & 15;
    int gnode = blockIdx.x * 16 + node_l;
    if (gnode < N_NODES) {
        float s[16];
#pragma unroll
        for (int k = 0; k < 16; ++k) s[k] = s1b[node_l][k];
        float h0 = sb1[g], h1 = sb1[g + 16];
#pragma unroll
        for (int k = 0; k < IN_CH; ++k) {
            h0 += s[k] * sW1[k * HID_CH + g];
            h1 += s[k] * sW1[k * HID_CH + g + 16];
        }
        hb[node_l][g]      = h0 > 0.f ? h0 : 0.f;
        hb[node_l][g + 16] = h1 > 0.f ? h1 : 0.f;
        float o = 0.f;
#pragma unroll
        for (int k = 0; k < HID_CH; ++k)
            o += hb[node_l][k] * sW2[k * LAT_CH + g];
        hwn[(size_t)gnode * 16 + g] = o * sdisb[node_l];
    }
}

// Layer-2 aggregation (k_agg v3, unchanged): 4 nodes/wave, dual window.
// outv[d*16+ch] = dis[d] * (sum_edges vin[s*16+ch] + vin[d*16+ch]) + bias
__global__ __launch_bounds__(256) void k_agg(const int* __restrict__ off,
                                             const int* __restrict__ srcs,
                                             const float* __restrict__ dis,
                                             const float* __restrict__ vin,
                                             const float* __restrict__ bias,  // may be null
                                             float* __restrict__ outv) {
    int wave = (blockIdx.x * 256 + threadIdx.x) >> 6;
    int lane = threadIdx.x & 63;
    int q    = lane & 3;
    int esub = (lane >> 2) & 3;
    int nsub = lane >> 4;
    int node = wave * 4 + nsub;
    bool valid = node < N_NODES;
    int beg = valid ? off[node] : 0;
    int end = valid ? off[node + 1] : 0;

    float ax = 0.f, ay = 0.f, az = 0.f, aw = 0.f;
    int k1 = beg + esub;
    int k2 = k1 + 4;
    int s1 = (k1 < end) ? srcs[k1] : -1;
    int s2 = (k2 < end) ? srcs[k2] : -1;
    for (int kb = beg; kb < end; kb += 8) {
        int kn = kb + 8 + esub;
        int sn1 = (kn < end)     ? srcs[kn]     : -1;
        int sn2 = (kn + 4 < end) ? srcs[kn + 4] : -1;
        float4 v1, v2;
        v1.x = v1.y = v1.z = v1.w = 0.f;
        v2.x = v2.y = v2.z = v2.w = 0.f;
        if (s1 >= 0) v1 = *((const float4*)(vin + (size_t)s1 * 16) + q);
        if (s2 >= 0) v2 = *((const float4*)(vin + (size_t)s2 * 16) + q);
        ax += v1.x + v2.x;
        ay += v1.y + v2.y;
        az += v1.z + v2.z;
        aw += v1.w + v2.w;
        s1 = sn1; s2 = sn2;
    }
#pragma unroll
    for (int m = 4; m <= 8; m <<= 1) {
        ax += __shfl_xor(ax, m);
        ay += __shfl_xor(ay, m);
        az += __shfl_xor(az, m);
        aw += __shfl_xor(aw, m);
    }
    if (esub == 0 && valid) {
        const float4 self = *((const float4*)(vin + (size_t)node * 16) + q);
        float d = dis[node];
        float4 r;
        r.x = d * (ax + self.x);
        r.y = d * (ay + self.y);
        r.z = d * (az + self.z);
        r.w = d * (aw + self.w);
        if (bias) {
            const float4 bq = ((const float4*)bias)[q];
            r.x += bq.x; r.y += bq.y; r.z += bq.z; r.w += bq.w;
        }
        *((float4*)(outv + (size_t)node * 16) + q) = r;
    }
}

extern "C" void kernel_launch(void* const* d_in, const int* in_sizes, int n_in,
                              void* d_out, int out_size, void* d_ws, size_t ws_size,
                              hipStream_t stream) {
    const float* x  = (const float*)d_in[0];
    const int*   ei = (const int*)d_in[1];
    const float* W1 = (const float*)d_in[2];
    const float* b1 = (const float*)d_in[3];
    const float* W2 = (const float*)d_in[4];
    const float* b2 = (const float*)d_in[5];
    float* out = (float*)d_out;

    const int* src = ei;
    const int* dst = ei + N_EDGES;

    // ws layout (bytes):
    //   bcur[391] @ 0 (pad 4096) | off[N+1] @ 4096 | dis[N] @ 404160
    //   srcs[E]   @ 804160 (12.8MB)
    //   buckets   @ 13604160 (391*8960*4 = 14,013,440 -> ends 27,617,600)
    //   hwn       @ 20004160 (inside buckets; written post-binB, buckets dead;
    //                          must NOT alias xn: agg_mlp reads xn, writes hwn)
    //   xn        @ 27617600 (6.4MB own region; binB writes while buckets live)
    char* ws = (char*)d_ws;
    int*   bcur    = (int*)(ws);
    int*   off     = (int*)(ws + 4096);
    float* dis     = (float*)(ws + 404160);
    int*   srcs    = (int*)(ws + 804160);
    int*   buckets = (int*)(ws + 13604160);
    float* hwn     = (float*)(ws + 20004160);
    float* xn      = (float*)(ws + 27617600);

    const int NB_A  = (N_EDGES + TILE - 1) / TILE;      // 391
    const int NB_W  = (N_NODES + 15) / 16;              // 4 nodes/wave, 4 waves/block

    k_zero_bcur<<<1,    512, 0, stream>>>(bcur);
    k_binA     <<<NB_A, 512, 0, stream>>>(src, dst, bcur, buckets);
    k_binB     <<<NBKT, 1024, 0, stream>>>(bcur, buckets, x, off, dis, srcs, xn);
    k_agg_mlp  <<<NB_W, 256, 0, stream>>>(off, srcs, dis, xn, W1, b1, W2, hwn);
    k_agg      <<<NB_W, 256, 0, stream>>>(off, srcs, dis, hwn, b2, out);
}